// Round 6
// baseline (348.630 us; speedup 1.0000x reference)
//
#include <hip/hip_runtime.h>

typedef unsigned short u16;
typedef unsigned int u32;
typedef __bf16 bf16x8 __attribute__((ext_vector_type(8)));
typedef float f32x4 __attribute__((ext_vector_type(4)));

#define MFMA_BF16(a, b, c) __builtin_amdgcn_mfma_f32_16x16x32_bf16((a), (b), (c), 0, 0, 0)

// log2-domain constants
#define QSCALE 0.18033688011112042f   // 0.125 * log2(e): folded into w_qkv Q-rows at prep
#define M0SHIFT 24.0f                 // fixed softmax shift (log2 domain)

// ---------- helpers ----------

__device__ __forceinline__ u16 f2bf(float f) {
  u32 u = __builtin_bit_cast(u32, f);
  u += 0x7fffu + ((u >> 16) & 1u);   // RNE
  return (u16)(u >> 16);
}

__device__ __forceinline__ void async_copy16(const void* g, void* l) {
  __builtin_amdgcn_global_load_lds(
      (__attribute__((address_space(1))) void*)g,
      (__attribute__((address_space(3))) void*)l, 16, 0, 0);
}

// ---------- kernel 0: fused fp32->bf16 converts + RoPE cos/sin table ----------

__global__ __launch_bounds__(256) void prep_kernel(
    const float* __restrict__ x_f, const float* __restrict__ wqkv_f,
    const float* __restrict__ wo_f, u16* __restrict__ xb,
    u16* __restrict__ wqkvb, u16* __restrict__ wob, float2* __restrict__ rope_t) {
  const int blk = blockIdx.x;
  if (blk < 12288) {
    const float* src;
    u16* dst;
    int base;
    float scale = 1.0f;
    if (blk < 8192)      { src = x_f;    dst = xb;    base = blk; }
    else if (blk < 11264){ src = wqkv_f; dst = wqkvb; base = blk - 8192;
                           if (base < 1024) scale = QSCALE; }  // Q rows
    else                 { src = wo_f;   dst = wob;   base = blk - 11264; }
    const int i = base * 1024 + threadIdx.x * 4;
    const float4 v = *(const float4*)(src + i);
    ushort4 o;
    o.x = f2bf(v.x * scale); o.y = f2bf(v.y * scale);
    o.z = f2bf(v.z * scale); o.w = f2bf(v.w * scale);
    *(ushort4*)(dst + i) = o;
  } else {
    const int idx = (blk - 12288) * 256 + threadIdx.x;  // [0, 65536)
    const int s = idx >> 5, i = idx & 31;
    const float invf = __builtin_amdgcn_exp2f(-(float)i * 0.41524101186092027f);
    float rev = (float)s * invf * 0.15915494309189535f;  // radians -> revolutions
    rev -= floorf(rev);
    rope_t[idx] = make_float2(__builtin_amdgcn_cosf(rev), __builtin_amdgcn_sinf(rev));
  }
}

// ---------- shared 128x128 GEMM-BT tile core (m97 structure) ----------

__device__ __forceinline__ void gemm_bt_tile(const u16* A, const u16* B, int K,
                                             int row0, int col0,
                                             u16* lds, f32x4 acc[4][4]) {
  const int tid = threadIdx.x;
  const int wave = tid >> 6;
  const int lane = tid & 63;
  const int fr = lane & 15;
  const int quad = lane >> 4;
  const int wm = (wave >> 1) * 64;
  const int wn = (wave & 1) * 64;
  u16* a_lds = lds;         // [128][32]
  u16* b_lds = lds + 4096;  // [128][32]

  f32x4 zero = {0.f, 0.f, 0.f, 0.f};
#pragma unroll
  for (int mt = 0; mt < 4; ++mt)
#pragma unroll
    for (int nt = 0; nt < 4; ++nt) acc[mt][nt] = zero;

  for (int k0 = 0; k0 < K; k0 += 32) {
    __syncthreads();
#pragma unroll
    for (int c = 0; c < 2; ++c) {
      const int ebase = wave * 1024 + c * 512;
      const int e = ebase + lane * 8;
      const int r = e >> 5;
      const int kk = e & 31;
      async_copy16(A + (size_t)(row0 + r) * K + k0 + kk, a_lds + ebase);
      async_copy16(B + (size_t)(col0 + r) * K + k0 + kk, b_lds + ebase);
    }
    __syncthreads();

    bf16x8 a_frag[4], b_frag[4];
#pragma unroll
    for (int t = 0; t < 4; ++t) {
      a_frag[t] = *(const bf16x8*)(a_lds + (wm + t * 16 + fr) * 32 + quad * 8);
      b_frag[t] = *(const bf16x8*)(b_lds + (wn + t * 16 + fr) * 32 + quad * 8);
    }
#pragma unroll
    for (int mt = 0; mt < 4; ++mt)
#pragma unroll
      for (int nt = 0; nt < 4; ++nt)
        acc[mt][nt] = MFMA_BF16(a_frag[mt], b_frag[nt], acc[mt][nt]);
  }
}

// ---------- kernel 1: QKV projection + RoPE, coalesced LDS-bounce epilogue ----

__global__ __launch_bounds__(256) void qkv_rope_kernel(
    const u16* __restrict__ x, const u16* __restrict__ w_qkv,
    const float2* __restrict__ rope_t,
    u16* __restrict__ q_ws, u16* __restrict__ k_ws, u16* __restrict__ vt_ws) {
  __shared__ u16 sbuf[128 * 136];  // gemm uses first 8192; epilogue full tile
  f32x4 acc[4][4];
  const int row0 = blockIdx.y * 128;  // M = 8192
  const int col0 = blockIdx.x * 128;  // N = 3072
  gemm_bt_tile(x, w_qkv, 1024, row0, col0, sbuf, acc);

  const int tid = threadIdx.x;
  const int wave = tid >> 6, lane = tid & 63;
  const int fr = lane & 15, quad = lane >> 4;
  const int wm = (wave >> 1) * 64, wn = (wave & 1) * 64;
  const int region = col0 >> 10;      // 0=Q 1=K 2=V (block-uniform)
  const int f0 = col0 & 1023;
  const int s0r = row0 & 2047;
  const int bb = row0 >> 11;

  __syncthreads();  // all waves done reading gemm LDS

  if (region < 2) {
#pragma unroll
    for (int mt = 0; mt < 4; ++mt) {
#pragma unroll
      for (int nt = 0; nt < 4; ++nt) {
        const int n = wn + nt * 16 + fr;
        const int d = n & 63;  // f0 is 128-aligned
#pragma unroll
        for (int r = 0; r < 4; ++r) {
          const int m = wm + mt * 16 + quad * 4 + r;
          const float own = acc[mt][nt][r];
          const float part = __shfl_xor(own, 1);
          const int s = s0r + m;
          const float2 cssn = rope_t[s * 32 + (d >> 1)];
          const float val = (d & 1) ? (part * cssn.y + own * cssn.x)
                                    : (own * cssn.x - part * cssn.y);
          sbuf[m * 136 + n] = f2bf(val);
        }
      }
    }
    __syncthreads();
    u16* dst = (region == 0) ? q_ws : k_ws;
    const int h0 = f0 >> 6;
#pragma unroll
    for (int j = 0; j < 8; ++j) {
      const int idx2 = j * 256 + tid;       // 0..2047
      const int hf = idx2 >> 10;            // head half
      const int m = (idx2 & 1023) >> 3;
      const int c8 = (idx2 & 7) * 8;
      const uint4 v = *(const uint4*)(sbuf + m * 136 + hf * 64 + c8);
      *(uint4*)(dst + ((size_t)(bb * 16 + h0 + hf) * 2048 + s0r + m) * 64 + c8) = v;
    }
  } else {
#pragma unroll
    for (int mt = 0; mt < 4; ++mt)
#pragma unroll
      for (int nt = 0; nt < 4; ++nt) {
        const int n = wn + nt * 16 + fr;
#pragma unroll
        for (int r = 0; r < 4; ++r) {
          const int m = wm + mt * 16 + quad * 4 + r;
          sbuf[n * 136 + m] = f2bf(acc[mt][nt][r]);
        }
      }
    __syncthreads();
    const int h0 = f0 >> 6;
#pragma unroll
    for (int j = 0; j < 8; ++j) {
      const int idx2 = j * 256 + tid;       // 0..2047
      const int n = idx2 >> 4;              // 0..127
      const int mc = (idx2 & 15) * 8;
      const int h = h0 + (n >> 6);
      const int d = n & 63;
      const uint4 v = *(const uint4*)(sbuf + n * 136 + mc);
      *(uint4*)(vt_ws + ((size_t)(bb * 16 + h) * 64 + d) * 2048 + s0r + mc) = v;
    }
  }
}

// ---------- kernel 2: causal flash attention, barrier-free ----------
// K and Vt B-fragments are read DIRECTLY from global (16B/lane pattern matches
// the MFMA B-operand layout); no LDS staging, no __syncthreads in the k-loop.
// Waves are fully independent with exact per-wave causal bounds. LDS holds only
// the wave-private P buffer. grid idx = qt_rev*64 + bh -> XCD = bh%8 under
// round-robin: each XCD's L2 serves its own 8 heads' K/V (8 x 512 KB = 4 MB).

__global__ __launch_bounds__(256, 4) void flash_attn_kernel(
    const u16* __restrict__ Q, const u16* __restrict__ K, const u16* __restrict__ Vt,
    const int* __restrict__ pad, u16* __restrict__ O) {
  const int S = 2048;
  const int idx = blockIdx.x;
  const int bh = idx & 63;
  const int b = bh >> 4, h = bh & 15;
  const int q0 = (15 - (idx >> 6)) * 128;  // longest q-tiles first
  const u16* Qh = Q + (size_t)bh * S * 64;
  const u16* Kh = K + (size_t)bh * S * 64;
  const u16* Vth = Vt + (size_t)bh * 64 * S;
  const int* padb = pad + b * S;
  const int tid = threadIdx.x, wave = tid >> 6, lane = tid & 63;
  const int fr = lane & 15, quad = lane >> 4;

  __shared__ u16 lds_p[4][32 * 76];  // per-wave P [q 32][76 pad]  19 KB

  const int qb = q0 + wave * 32;  // wave's first q row
  bf16x8 qfrag[2][2];
#pragma unroll
  for (int mt = 0; mt < 2; ++mt)
#pragma unroll
    for (int kk = 0; kk < 2; ++kk)
      qfrag[mt][kk] =
          *(const bf16x8*)(Qh + (size_t)(qb + mt * 16 + fr) * 64 + kk * 32 + quad * 8);

  bf16x8 ones;
#pragma unroll
  for (int j = 0; j < 8; ++j) ones[j] = (__bf16)1.0f;

  f32x4 zero = {0.f, 0.f, 0.f, 0.f};
  f32x4 o_acc[2][4], lacc[2];
#pragma unroll
  for (int mt = 0; mt < 2; ++mt) {
    lacc[mt] = zero;
#pragma unroll
    for (int nt = 0; nt < 4; ++nt) o_acc[mt][nt] = zero;
  }

  u16* pw = lds_p[wave];
  const float NEG = -__builtin_inff();

  for (int k0 = 0; k0 <= qb + 31; k0 += 64) {  // exact per-wave causal bound
    const bool needMask = (k0 + 63 > qb);
    // S2 = Qs K^T (log2 domain), K fragments straight from global/L2
#pragma unroll
    for (int nt = 0; nt < 4; ++nt) {
      const int col = k0 + nt * 16 + fr;
      const float bias = padb[col] ? -M0SHIFT : NEG;
      f32x4 s0 = zero, s1 = zero;
#pragma unroll
      for (int kk = 0; kk < 2; ++kk) {
        bf16x8 bfrag =
            *(const bf16x8*)(Kh + (size_t)col * 64 + kk * 32 + quad * 8);
        s0 = MFMA_BF16(qfrag[0][kk], bfrag, s0);
        s1 = MFMA_BF16(qfrag[1][kk], bfrag, s1);
      }
#pragma unroll
      for (int r = 0; r < 4; ++r) {
        float v0 = s0[r] + bias;
        float v1 = s1[r] + bias;
        if (needMask) {
          if (col > qb + quad * 4 + r) v0 = NEG;
          if (col > qb + 16 + quad * 4 + r) v1 = NEG;
        }
        const float p0 = __builtin_amdgcn_exp2f(v0);
        const float p1 = __builtin_amdgcn_exp2f(v1);
        pw[(quad * 4 + r) * 76 + nt * 16 + fr] =
            (u16)(__builtin_bit_cast(u32, p0) >> 16);
        pw[(16 + quad * 4 + r) * 76 + nt * 16 + fr] =
            (u16)(__builtin_bit_cast(u32, p1) >> 16);
      }
    }
    // per-wave P bounce complete before A-frag reads (wave-private buffer)
    asm volatile("s_waitcnt lgkmcnt(0)" ::: "memory");

    // O += P*V ; l += P*ones  -- V fragments straight from global/L2
#pragma unroll
    for (int kk = 0; kk < 2; ++kk) {
      bf16x8 p0 = *(const bf16x8*)(pw + fr * 76 + kk * 32 + quad * 8);
      bf16x8 p1 = *(const bf16x8*)(pw + (16 + fr) * 76 + kk * 32 + quad * 8);
      lacc[0] = MFMA_BF16(p0, ones, lacc[0]);
      lacc[1] = MFMA_BF16(p1, ones, lacc[1]);
#pragma unroll
      for (int nt = 0; nt < 4; ++nt) {
        bf16x8 vf = *(const bf16x8*)(Vth + (size_t)(nt * 16 + fr) * 2048 + k0 +
                                     kk * 32 + quad * 8);
        o_acc[0][nt] = MFMA_BF16(p0, vf, o_acc[0][nt]);
        o_acc[1][nt] = MFMA_BF16(p1, vf, o_acc[1][nt]);
      }
    }
  }

  // epilogue: normalize, write [B][S][H*64]
#pragma unroll
  for (int mt = 0; mt < 2; ++mt)
#pragma unroll
    for (int r = 0; r < 4; ++r) {
      const int row = qb + mt * 16 + quad * 4 + r;
      const float l = lacc[mt][r];
      const float rl = (l > 0.f) ? (1.0f / l) : 0.f;
#pragma unroll
      for (int nt = 0; nt < 4; ++nt)
        O[(size_t)(b * S + row) * 1024 + h * 64 + nt * 16 + fr] =
            f2bf(o_acc[mt][nt][r] * rl);
    }
}

// ---------- kernel 3: output projection (writes fp32 to d_out) ----------

__global__ __launch_bounds__(256) void oproj_kernel(
    const u16* __restrict__ A, const u16* __restrict__ w_o, float* __restrict__ out) {
  __shared__ u16 lds[8192];
  f32x4 acc[4][4];
  const int row0 = blockIdx.y * 128;
  const int col0 = blockIdx.x * 128;
  gemm_bt_tile(A, w_o, 1024, row0, col0, lds, acc);
  const int tid = threadIdx.x;
  const int wave = tid >> 6, lane = tid & 63;
  const int fr = lane & 15, quad = lane >> 4;
  const int wm = (wave >> 1) * 64, wn = (wave & 1) * 64;
#pragma unroll
  for (int mt = 0; mt < 4; ++mt)
#pragma unroll
    for (int nt = 0; nt < 4; ++nt) {
      const int ncol = col0 + wn + nt * 16 + fr;
#pragma unroll
      for (int r = 0; r < 4; ++r) {
        const int mrow = row0 + wm + mt * 16 + quad * 4 + r;
        out[(size_t)mrow * 1024 + ncol] = acc[mt][nt][r];
      }
    }
}

// ---------- launch ----------

extern "C" void kernel_launch(void* const* d_in, const int* in_sizes, int n_in,
                              void* d_out, int out_size, void* d_ws, size_t ws_size,
                              hipStream_t stream) {
  const float* x_f = (const float*)d_in[0];     // [4][2048][1024] fp32
  const int* pad = (const int*)d_in[1];         // [4][2048] int32
  const float* wqkv_f = (const float*)d_in[2];  // [3072][1024] fp32
  const float* wo_f = (const float*)d_in[3];    // [1024][1024] fp32
  float* out = (float*)d_out;                   // [4][2048][1024] fp32

  const int NX = 4 * 2048 * 1024;
  const int NWQKV = 3072 * 1024;
  const int NWO = 1024 * 1024;
  const size_t HSZ = (size_t)4 * 16 * 2048 * 64;  // 8M elems per head-tensor

  u16* xb = (u16*)d_ws;            // 16 MB
  u16* wqkvb = xb + NX;            // 6 MB
  u16* wob = wqkvb + NWQKV;        // 2 MB
  u16* q_ws = wob + NWO;           // 16 MB  [B][H][S][64] (pre-scaled, roped)
  u16* k_ws = q_ws + HSZ;          // 16 MB  [B][H][S][64] (roped)
  u16* vt_ws = k_ws + HSZ;         // 16 MB  [B][H][64][S] (transposed)
  u16* attn_ws = vt_ws + HSZ;      // 16 MB  [B*S][D]
  float2* rope_t = (float2*)(attn_ws + HSZ);  // 512 KB [2048][32]

  dim3 blk(256);
  prep_kernel<<<dim3(12544), blk, 0, stream>>>(x_f, wqkv_f, wo_f, xb, wqkvb, wob, rope_t);
  qkv_rope_kernel<<<dim3(24, 64), blk, 0, stream>>>(xb, wqkvb, rope_t, q_ws, k_ws, vt_ws);
  flash_attn_kernel<<<dim3(1024), blk, 0, stream>>>(q_ws, k_ws, vt_ws, pad, attn_ws);
  oproj_kernel<<<dim3(8, 64), blk, 0, stream>>>(attn_ws, wob, out);
}

// Round 7
// 300.616 us; speedup vs baseline: 1.1597x; 1.1597x over previous
//
#include <hip/hip_runtime.h>

typedef unsigned short u16;
typedef unsigned int u32;
typedef __bf16 bf16x8 __attribute__((ext_vector_type(8)));
typedef float f32x4 __attribute__((ext_vector_type(4)));

#define MFMA_BF16(a, b, c) __builtin_amdgcn_mfma_f32_16x16x32_bf16((a), (b), (c), 0, 0, 0)

// log2-domain constants
#define QSCALE 0.18033688011112042f   // 0.125 * log2(e): folded into w_qkv Q-rows at prep
#define M0SHIFT 24.0f                 // fixed softmax shift (log2 domain)

// ---------- helpers ----------

__device__ __forceinline__ u16 f2bf(float f) {
  u32 u = __builtin_bit_cast(u32, f);
  u += 0x7fffu + ((u >> 16) & 1u);   // RNE
  return (u16)(u >> 16);
}

__device__ __forceinline__ void async_copy16(const void* g, void* l) {
  __builtin_amdgcn_global_load_lds(
      (__attribute__((address_space(1))) void*)g,
      (__attribute__((address_space(3))) void*)l, 16, 0, 0);
}

// ---------- kernel 0: fused fp32->bf16 converts + RoPE cos/sin table ----------

__global__ __launch_bounds__(256) void prep_kernel(
    const float* __restrict__ x_f, const float* __restrict__ wqkv_f,
    const float* __restrict__ wo_f, u16* __restrict__ xb,
    u16* __restrict__ wqkvb, u16* __restrict__ wob, float2* __restrict__ rope_t) {
  const int blk = blockIdx.x;
  if (blk < 12288) {
    const float* src;
    u16* dst;
    int base;
    float scale = 1.0f;
    if (blk < 8192)      { src = x_f;    dst = xb;    base = blk; }
    else if (blk < 11264){ src = wqkv_f; dst = wqkvb; base = blk - 8192;
                           if (base < 1024) scale = QSCALE; }  // Q rows
    else                 { src = wo_f;   dst = wob;   base = blk - 11264; }
    const int i = base * 1024 + threadIdx.x * 4;
    const float4 v = *(const float4*)(src + i);
    ushort4 o;
    o.x = f2bf(v.x * scale); o.y = f2bf(v.y * scale);
    o.z = f2bf(v.z * scale); o.w = f2bf(v.w * scale);
    *(ushort4*)(dst + i) = o;
  } else {
    const int idx = (blk - 12288) * 256 + threadIdx.x;  // [0, 65536)
    const int s = idx >> 5, i = idx & 31;
    const float invf = __builtin_amdgcn_exp2f(-(float)i * 0.41524101186092027f);
    float rev = (float)s * invf * 0.15915494309189535f;  // radians -> revolutions
    rev -= floorf(rev);
    rope_t[idx] = make_float2(__builtin_amdgcn_cosf(rev), __builtin_amdgcn_sinf(rev));
  }
}

// ---------- shared 128x128 GEMM-BT tile core (m97 structure) ----------

__device__ __forceinline__ void gemm_bt_tile(const u16* A, const u16* B, int K,
                                             int row0, int col0,
                                             u16* lds, f32x4 acc[4][4]) {
  const int tid = threadIdx.x;
  const int wave = tid >> 6;
  const int lane = tid & 63;
  const int fr = lane & 15;
  const int quad = lane >> 4;
  const int wm = (wave >> 1) * 64;
  const int wn = (wave & 1) * 64;
  u16* a_lds = lds;         // [128][32]
  u16* b_lds = lds + 4096;  // [128][32]

  f32x4 zero = {0.f, 0.f, 0.f, 0.f};
#pragma unroll
  for (int mt = 0; mt < 4; ++mt)
#pragma unroll
    for (int nt = 0; nt < 4; ++nt) acc[mt][nt] = zero;

  for (int k0 = 0; k0 < K; k0 += 32) {
    __syncthreads();
#pragma unroll
    for (int c = 0; c < 2; ++c) {
      const int ebase = wave * 1024 + c * 512;
      const int e = ebase + lane * 8;
      const int r = e >> 5;
      const int kk = e & 31;
      async_copy16(A + (size_t)(row0 + r) * K + k0 + kk, a_lds + ebase);
      async_copy16(B + (size_t)(col0 + r) * K + k0 + kk, b_lds + ebase);
    }
    __syncthreads();

    bf16x8 a_frag[4], b_frag[4];
#pragma unroll
    for (int t = 0; t < 4; ++t) {
      a_frag[t] = *(const bf16x8*)(a_lds + (wm + t * 16 + fr) * 32 + quad * 8);
      b_frag[t] = *(const bf16x8*)(b_lds + (wn + t * 16 + fr) * 32 + quad * 8);
    }
#pragma unroll
    for (int mt = 0; mt < 4; ++mt)
#pragma unroll
      for (int nt = 0; nt < 4; ++nt)
        acc[mt][nt] = MFMA_BF16(a_frag[mt], b_frag[nt], acc[mt][nt]);
  }
}

// ---------- kernel 1: QKV projection + RoPE, coalesced LDS-bounce epilogue ----

__global__ __launch_bounds__(256) void qkv_rope_kernel(
    const u16* __restrict__ x, const u16* __restrict__ w_qkv,
    const float2* __restrict__ rope_t,
    u16* __restrict__ q_ws, u16* __restrict__ k_ws, u16* __restrict__ vt_ws) {
  __shared__ u16 sbuf[128 * 136];  // gemm uses first 8192; epilogue full tile
  f32x4 acc[4][4];
  const int row0 = blockIdx.y * 128;  // M = 8192
  const int col0 = blockIdx.x * 128;  // N = 3072
  gemm_bt_tile(x, w_qkv, 1024, row0, col0, sbuf, acc);

  const int tid = threadIdx.x;
  const int wave = tid >> 6, lane = tid & 63;
  const int fr = lane & 15, quad = lane >> 4;
  const int wm = (wave >> 1) * 64, wn = (wave & 1) * 64;
  const int region = col0 >> 10;      // 0=Q 1=K 2=V (block-uniform)
  const int f0 = col0 & 1023;
  const int s0r = row0 & 2047;
  const int bb = row0 >> 11;

  __syncthreads();  // all waves done reading gemm LDS

  if (region < 2) {
#pragma unroll
    for (int mt = 0; mt < 4; ++mt) {
#pragma unroll
      for (int nt = 0; nt < 4; ++nt) {
        const int n = wn + nt * 16 + fr;
        const int d = n & 63;  // f0 is 128-aligned
#pragma unroll
        for (int r = 0; r < 4; ++r) {
          const int m = wm + mt * 16 + quad * 4 + r;
          const float own = acc[mt][nt][r];
          const float part = __shfl_xor(own, 1);
          const int s = s0r + m;
          const float2 cssn = rope_t[s * 32 + (d >> 1)];
          const float val = (d & 1) ? (part * cssn.y + own * cssn.x)
                                    : (own * cssn.x - part * cssn.y);
          sbuf[m * 136 + n] = f2bf(val);
        }
      }
    }
    __syncthreads();
    u16* dst = (region == 0) ? q_ws : k_ws;
    const int h0 = f0 >> 6;
#pragma unroll
    for (int j = 0; j < 8; ++j) {
      const int idx2 = j * 256 + tid;       // 0..2047
      const int hf = idx2 >> 10;            // head half
      const int m = (idx2 & 1023) >> 3;
      const int c8 = (idx2 & 7) * 8;
      const uint4 v = *(const uint4*)(sbuf + m * 136 + hf * 64 + c8);
      *(uint4*)(dst + ((size_t)(bb * 16 + h0 + hf) * 2048 + s0r + m) * 64 + c8) = v;
    }
  } else {
#pragma unroll
    for (int mt = 0; mt < 4; ++mt)
#pragma unroll
      for (int nt = 0; nt < 4; ++nt) {
        const int n = wn + nt * 16 + fr;
#pragma unroll
        for (int r = 0; r < 4; ++r) {
          const int m = wm + mt * 16 + quad * 4 + r;
          sbuf[n * 136 + m] = f2bf(acc[mt][nt][r]);
        }
      }
    __syncthreads();
    const int h0 = f0 >> 6;
#pragma unroll
    for (int j = 0; j < 8; ++j) {
      const int idx2 = j * 256 + tid;       // 0..2047
      const int n = idx2 >> 4;              // 0..127
      const int mc = (idx2 & 15) * 8;
      const int h = h0 + (n >> 6);
      const int d = n & 63;
      const uint4 v = *(const uint4*)(sbuf + n * 136 + mc);
      *(uint4*)(vt_ws + ((size_t)(bb * 16 + h) * 64 + d) * 2048 + s0r + mc) = v;
    }
  }
}

// ---------- kernel 2: causal flash attention, software-pipelined ----------
// K: LDS double-buffer via global_load_lds; the DMA for tile i is issued in
// iter i-1, so the vmcnt drain implied by the single per-iter __syncthreads
// waits on an already-landed transfer (cheap barrier). V: B-fragments read
// directly from global/L2 (pattern matches MFMA B-operand), manually hoisted
// above the exp/P chain so their latency overlaps softmax VALU work.
// grid idx = qt_rev*64 + bh; LDS 35.8 KB -> 4 blocks/CU; grid 1024 -> all
// blocks co-resident (zero tail).

__global__ __launch_bounds__(256, 4) void flash_attn_kernel(
    const u16* __restrict__ Q, const u16* __restrict__ K, const u16* __restrict__ Vt,
    const int* __restrict__ pad, u16* __restrict__ O) {
  const int S = 2048;
  const int idx = blockIdx.x;
  const int bh = idx & 63;
  const int b = bh >> 4, h = bh & 15;
  const int q0 = (15 - (idx >> 6)) * 128;  // longest q-tiles first
  const u16* Qh = Q + (size_t)bh * S * 64;
  const u16* Kh = K + (size_t)bh * S * 64;
  const u16* Vth = Vt + (size_t)bh * 64 * S;
  const int* padb = pad + b * S;
  const int tid = threadIdx.x, wave = tid >> 6, lane = tid & 63;
  const int fr = lane & 15, quad = lane >> 4;

  __shared__ u16 lds_k[2][2 * 64 * 32];  // K tile dbuf [kc][kpos 64][d 32], 2x8 KB
  __shared__ u16 lds_p[4][32 * 76];      // per-wave P [q 32][76 pad], 19 KB

  const int qb = q0 + wave * 32;  // wave's first q row
  bf16x8 qfrag[2][2];
#pragma unroll
  for (int mt = 0; mt < 2; ++mt)
#pragma unroll
    for (int kk = 0; kk < 2; ++kk)
      qfrag[mt][kk] =
          *(const bf16x8*)(Qh + (size_t)(qb + mt * 16 + fr) * 64 + kk * 32 + quad * 8);

  bf16x8 ones;
#pragma unroll
  for (int j = 0; j < 8; ++j) ones[j] = (__bf16)1.0f;

  f32x4 zero = {0.f, 0.f, 0.f, 0.f};
  f32x4 o_acc[2][4], lacc[2];
#pragma unroll
  for (int mt = 0; mt < 2; ++mt) {
    lacc[mt] = zero;
#pragma unroll
    for (int nt = 0; nt < 4; ++nt) o_acc[mt][nt] = zero;
  }

  u16* pw = lds_p[wave];
  const float NEG = -__builtin_inff();
  const int kend = q0 + 127;  // block-uniform last needed column

  // prologue: stage K tile 0 into buf 0
#pragma unroll
  for (int it = 0; it < 2; ++it) {
    const int slot = it * 256 + tid;
    const int kc = slot >> 8, rem = slot & 255;
    const int rr = rem >> 2, cc = (rem & 3) * 8;
    async_copy16(Kh + (size_t)rr * 64 + kc * 32 + cc, lds_k[0] + slot * 8);
  }

  for (int k0 = 0; k0 <= kend; k0 += 64) {
    const int buf = (k0 >> 6) & 1;
    __syncthreads();  // drains tile-k0 DMA (issued a full iter ago) + protects dbuf
    if (k0 + 64 <= kend) {  // issue next tile's DMA into the other buffer
#pragma unroll
      for (int it = 0; it < 2; ++it) {
        const int slot = it * 256 + tid;
        const int kc = slot >> 8, rem = slot & 255;
        const int rr = rem >> 2, cc = (rem & 3) * 8;
        async_copy16(Kh + (size_t)(k0 + 64 + rr) * 64 + kc * 32 + cc,
                     lds_k[buf ^ 1] + slot * 8);
      }
    }
    if (k0 > qb + 31) continue;  // wave-uniform skip (still hits every barrier)
    const bool needMask = (k0 + 63 > qb);
    const u16* kb = lds_k[buf];

    // padding bias (4 int loads, issued first)
    float bias[4];
#pragma unroll
    for (int nt = 0; nt < 4; ++nt)
      bias[nt] = padb[k0 + nt * 16 + fr] ? -M0SHIFT : NEG;

    // manual hoist: V fragments straight from global/L2, consumed after exp
    bf16x8 vf[2][4];
#pragma unroll
    for (int kk = 0; kk < 2; ++kk)
#pragma unroll
      for (int nt = 0; nt < 4; ++nt)
        vf[kk][nt] = *(const bf16x8*)(Vth + (size_t)(nt * 16 + fr) * 2048 + k0 +
                                      kk * 32 + quad * 8);

    // S2 = Qs K^T (log2 domain) from LDS; exp2; P -> wave-private LDS
#pragma unroll
    for (int nt = 0; nt < 4; ++nt) {
      f32x4 s0 = zero, s1 = zero;
#pragma unroll
      for (int kk = 0; kk < 2; ++kk) {
        bf16x8 bfrag = *(const bf16x8*)(kb + (kk * 64 + nt * 16 + fr) * 32 + quad * 8);
        s0 = MFMA_BF16(qfrag[0][kk], bfrag, s0);
        s1 = MFMA_BF16(qfrag[1][kk], bfrag, s1);
      }
      const int col = k0 + nt * 16 + fr;
#pragma unroll
      for (int r = 0; r < 4; ++r) {
        float v0 = s0[r] + bias[nt];
        float v1 = s1[r] + bias[nt];
        if (needMask) {
          if (col > qb + quad * 4 + r) v0 = NEG;
          if (col > qb + 16 + quad * 4 + r) v1 = NEG;
        }
        const float p0 = __builtin_amdgcn_exp2f(v0);
        const float p1 = __builtin_amdgcn_exp2f(v1);
        pw[(quad * 4 + r) * 76 + nt * 16 + fr] =
            (u16)(__builtin_bit_cast(u32, p0) >> 16);
        pw[(16 + quad * 4 + r) * 76 + nt * 16 + fr] =
            (u16)(__builtin_bit_cast(u32, p1) >> 16);
      }
    }
    // per-wave P bounce complete before A-frag reads (wave-private buffer)
    asm volatile("s_waitcnt lgkmcnt(0)" ::: "memory");

    // O += P*V ; l += P*ones
#pragma unroll
    for (int kk = 0; kk < 2; ++kk) {
      bf16x8 p0 = *(const bf16x8*)(pw + fr * 76 + kk * 32 + quad * 8);
      bf16x8 p1 = *(const bf16x8*)(pw + (16 + fr) * 76 + kk * 32 + quad * 8);
      lacc[0] = MFMA_BF16(p0, ones, lacc[0]);
      lacc[1] = MFMA_BF16(p1, ones, lacc[1]);
#pragma unroll
      for (int nt = 0; nt < 4; ++nt) {
        o_acc[0][nt] = MFMA_BF16(p0, vf[kk][nt], o_acc[0][nt]);
        o_acc[1][nt] = MFMA_BF16(p1, vf[kk][nt], o_acc[1][nt]);
      }
    }
  }

  // epilogue: normalize, write [B][S][H*64]
#pragma unroll
  for (int mt = 0; mt < 2; ++mt)
#pragma unroll
    for (int r = 0; r < 4; ++r) {
      const int row = qb + mt * 16 + quad * 4 + r;
      const float l = lacc[mt][r];
      const float rl = (l > 0.f) ? (1.0f / l) : 0.f;
#pragma unroll
      for (int nt = 0; nt < 4; ++nt)
        O[(size_t)(b * S + row) * 1024 + h * 64 + nt * 16 + fr] =
            f2bf(o_acc[mt][nt][r] * rl);
    }
}

// ---------- kernel 3: output projection (writes fp32 to d_out) ----------

__global__ __launch_bounds__(256) void oproj_kernel(
    const u16* __restrict__ A, const u16* __restrict__ w_o, float* __restrict__ out) {
  __shared__ u16 lds[8192];
  f32x4 acc[4][4];
  const int row0 = blockIdx.y * 128;
  const int col0 = blockIdx.x * 128;
  gemm_bt_tile(A, w_o, 1024, row0, col0, lds, acc);
  const int tid = threadIdx.x;
  const int wave = tid >> 6, lane = tid & 63;
  const int fr = lane & 15, quad = lane >> 4;
  const int wm = (wave >> 1) * 64, wn = (wave & 1) * 64;
#pragma unroll
  for (int mt = 0; mt < 4; ++mt)
#pragma unroll
    for (int nt = 0; nt < 4; ++nt) {
      const int ncol = col0 + wn + nt * 16 + fr;
#pragma unroll
      for (int r = 0; r < 4; ++r) {
        const int mrow = row0 + wm + mt * 16 + quad * 4 + r;
        out[(size_t)mrow * 1024 + ncol] = acc[mt][nt][r];
      }
    }
}

// ---------- launch ----------

extern "C" void kernel_launch(void* const* d_in, const int* in_sizes, int n_in,
                              void* d_out, int out_size, void* d_ws, size_t ws_size,
                              hipStream_t stream) {
  const float* x_f = (const float*)d_in[0];     // [4][2048][1024] fp32
  const int* pad = (const int*)d_in[1];         // [4][2048] int32
  const float* wqkv_f = (const float*)d_in[2];  // [3072][1024] fp32
  const float* wo_f = (const float*)d_in[3];    // [1024][1024] fp32
  float* out = (float*)d_out;                   // [4][2048][1024] fp32

  const int NX = 4 * 2048 * 1024;
  const int NWQKV = 3072 * 1024;
  const int NWO = 1024 * 1024;
  const size_t HSZ = (size_t)4 * 16 * 2048 * 64;  // 8M elems per head-tensor

  u16* xb = (u16*)d_ws;            // 16 MB
  u16* wqkvb = xb + NX;            // 6 MB
  u16* wob = wqkvb + NWQKV;        // 2 MB
  u16* q_ws = wob + NWO;           // 16 MB  [B][H][S][64] (pre-scaled, roped)
  u16* k_ws = q_ws + HSZ;          // 16 MB  [B][H][S][64] (roped)
  u16* vt_ws = k_ws + HSZ;         // 16 MB  [B][H][64][S] (transposed)
  u16* attn_ws = vt_ws + HSZ;      // 16 MB  [B*S][D]
  float2* rope_t = (float2*)(attn_ws + HSZ);  // 512 KB [2048][32]

  dim3 blk(256);
  prep_kernel<<<dim3(12544), blk, 0, stream>>>(x_f, wqkv_f, wo_f, xb, wqkvb, wob, rope_t);
  qkv_rope_kernel<<<dim3(24, 64), blk, 0, stream>>>(xb, wqkvb, rope_t, q_ws, k_ws, vt_ws);
  flash_attn_kernel<<<dim3(1024), blk, 0, stream>>>(q_ws, k_ws, vt_ws, pad, attn_ws);
  oproj_kernel<<<dim3(8, 64), blk, 0, stream>>>(attn_ws, wob, out);
}